// Round 8
// baseline (301.506 us; speedup 1.0000x reference)
//
#include <hip/hip_runtime.h>
#include <hip/hip_bf16.h>

// Shapes fixed by the reference: B=32, T=1024, F=4096, D=384.
#define B_ 32
#define T_ 1024
#define F_ 4096
#define D_ 384
#define D4_ 96   // D/4 float4 per row

// Native clang vector types — required by __builtin_nontemporal_store.
typedef float vfloat4 __attribute__((ext_vector_type(4)));
typedef int   vint4   __attribute__((ext_vector_type(4)));

// Kernel 1: per-batch run-count prefix sum.
// idx[b][j] = idx[b][j-1] + (align[b][j] != align[b][j-1]), idx[b][0] = 0.
// Equivalent to the reference's sequential pointer walk because align is
// repeat(text, dur) with adjacent text phones guaranteed distinct, so the
// walker's `before` always equals align[j] after step j. text_phone unused.
__global__ __launch_bounds__(256) void scan_idx_kernel(
    const int* __restrict__ align, int* __restrict__ idx)
{
    const int b = blockIdx.x;
    const int t = threadIdx.x;
    const int CHUNK = F_ / 256;  // 16
    const int* a = align + (size_t)b * F_;
    int*       o = idx   + (size_t)b * F_;
    const int start = t * CHUNK;

    int vals[CHUNK];
#pragma unroll
    for (int i = 0; i < CHUNK; ++i) vals[i] = a[start + i];

    int prev = (start == 0) ? vals[0] : a[start - 1];

    int loc[CHUNK];
    int cnt = 0;
#pragma unroll
    for (int i = 0; i < CHUNK; ++i) {
        cnt += (vals[i] != prev) ? 1 : 0;
        loc[i] = cnt;
        prev = vals[i];
    }

    __shared__ int s[256];
    s[t] = cnt;
    __syncthreads();
    for (int off = 1; off < 256; off <<= 1) {
        int v = (t >= off) ? s[t - off] : 0;
        __syncthreads();
        s[t] += v;
        __syncthreads();
    }
    const int base = s[t] - cnt;  // exclusive prefix

#pragma unroll
    for (int i = 0; i < CHUNK; ++i) o[start + i] = base + loc[i];
}

// Kernel 2 (ILP-8, nt stores, NO swizzle — unchanged from round 7).
// ROUND-8 PROBE: launched TWICE per iteration (idempotent — reads only
// enc/idx/pitch/beats, writes out; second run reproduces identical output).
// The dur_us delta vs round 7 (262.8) directly measures postnet's duration P,
// which the harness's top-5 counter window (all ~120µs poison fills) hides.
// This resolves whether postnet is ~115µs (big headroom) or ~45µs (near its
// 192MiB-store + 48MiB-gather roofline, total dominated by harness fill).
__global__ __launch_bounds__(256) void postnet_kernel(
    const vfloat4* __restrict__ enc,     // [B*T*96]
    const vint4*   __restrict__ idx4,    // [B*F/4]
    const vfloat4* __restrict__ pitch4,  // [B*F/4]
    const vfloat4* __restrict__ beats4,  // [B*F/4]
    const vfloat4* __restrict__ wp, const vfloat4* __restrict__ bp,
    const vfloat4* __restrict__ wb, const vfloat4* __restrict__ bb,
    const vfloat4* __restrict__ wq, const vfloat4* __restrict__ bq,
    vfloat4* __restrict__ out)           // [B*F*96]
{
    const int g   = blockIdx.x * 256 + threadIdx.x;  // < (B*F/8)*96 = 1,572,864
    const int d4  = g % D4_;
    const int rg  = g / D4_;            // 8-frame group id in [0, B*F/8)
    const int rf0 = rg * 8;             // first frame of the group
    const int f0  = rf0 & (F_ - 1);
    const int b   = rf0 >> 12;          // F = 4096 = 2^12

    // Two vector loads each for idx / pitch / beats (frames rf0..rf0+7).
    const vint4   e4a = idx4  [2 * rg],  e4b = idx4  [2 * rg + 1];
    const vfloat4 pva = pitch4[2 * rg],  pvb = pitch4[2 * rg + 1];
    const vfloat4 bva = beats4[2 * rg],  bvb = beats4[2 * rg + 1];

    const vfloat4 w1 = wp[d4], w2 = wb[d4], w3 = wq[d4];
    const vfloat4 osum = bp[d4] + bb[d4] + bq[d4];

    // Issue all 8 gathers up front — independent chains.
    const vfloat4* encb = enc + (size_t)b * T_ * D4_ + d4;
    const vfloat4 ev0 = encb[(size_t)e4a.x * D4_];
    const vfloat4 ev1 = encb[(size_t)e4a.y * D4_];
    const vfloat4 ev2 = encb[(size_t)e4a.z * D4_];
    const vfloat4 ev3 = encb[(size_t)e4a.w * D4_];
    const vfloat4 ev4 = encb[(size_t)e4b.x * D4_];
    const vfloat4 ev5 = encb[(size_t)e4b.y * D4_];
    const vfloat4 ev6 = encb[(size_t)e4b.z * D4_];
    const vfloat4 ev7 = encb[(size_t)e4b.w * D4_];

    const float fv = (float)f0;
    vfloat4 r0 = ev0 + pva.x * w1 + bva.x * w2 + (fv + 0.f) * w3 + osum;
    vfloat4 r1 = ev1 + pva.y * w1 + bva.y * w2 + (fv + 1.f) * w3 + osum;
    vfloat4 r2 = ev2 + pva.z * w1 + bva.z * w2 + (fv + 2.f) * w3 + osum;
    vfloat4 r3 = ev3 + pva.w * w1 + bva.w * w2 + (fv + 3.f) * w3 + osum;
    vfloat4 r4 = ev4 + pvb.x * w1 + bvb.x * w2 + (fv + 4.f) * w3 + osum;
    vfloat4 r5 = ev5 + pvb.y * w1 + bvb.y * w2 + (fv + 5.f) * w3 + osum;
    vfloat4 r6 = ev6 + pvb.z * w1 + bvb.z * w2 + (fv + 6.f) * w3 + osum;
    vfloat4 r7 = ev7 + pvb.w * w1 + bvb.w * w2 + (fv + 7.f) * w3 + osum;

    vfloat4* o = out + (size_t)rf0 * D4_ + d4;
    __builtin_nontemporal_store(r0, o + 0 * D4_);
    __builtin_nontemporal_store(r1, o + 1 * D4_);
    __builtin_nontemporal_store(r2, o + 2 * D4_);
    __builtin_nontemporal_store(r3, o + 3 * D4_);
    __builtin_nontemporal_store(r4, o + 4 * D4_);
    __builtin_nontemporal_store(r5, o + 5 * D4_);
    __builtin_nontemporal_store(r6, o + 6 * D4_);
    __builtin_nontemporal_store(r7, o + 7 * D4_);
}

extern "C" void kernel_launch(void* const* d_in, const int* in_sizes, int n_in,
                              void* d_out, int out_size, void* d_ws, size_t ws_size,
                              hipStream_t stream) {
    const float* enc     = (const float*)d_in[0];   // [B,T,D] f32
    const int*   align   = (const int*)  d_in[1];   // [B,F]
    // d_in[2] = text_phone — unused (see scan_idx_kernel comment)
    const float* pitch   = (const float*)d_in[3];   // [B,F]
    const float* beats   = (const float*)d_in[4];   // [B,F]
    const float* w_pitch = (const float*)d_in[5];
    const float* b_pitch = (const float*)d_in[6];
    const float* w_beats = (const float*)d_in[7];
    const float* b_beats = (const float*)d_in[8];
    const float* w_pos   = (const float*)d_in[9];
    const float* b_pos   = (const float*)d_in[10];

    int* idx_ws = (int*)d_ws;  // B*F ints = 512 KB, 16B-aligned (ws base)

    scan_idx_kernel<<<B_, 256, 0, stream>>>(align, idx_ws);

    const int total = (B_ * F_ / 8) * D4_;    // 1,572,864 threads
    const int blocks = total / 256;           // 6,144 exact

    // PROBE: two identical launches. dur_us delta vs round 7 == postnet time.
    for (int rep = 0; rep < 2; ++rep) {
        postnet_kernel<<<blocks, 256, 0, stream>>>(
            (const vfloat4*)enc, (const vint4*)idx_ws,
            (const vfloat4*)pitch, (const vfloat4*)beats,
            (const vfloat4*)w_pitch, (const vfloat4*)b_pitch,
            (const vfloat4*)w_beats, (const vfloat4*)b_beats,
            (const vfloat4*)w_pos,   (const vfloat4*)b_pos,
            (vfloat4*)d_out);
    }
}

// Round 9
// 261.595 us; speedup vs baseline: 1.1526x; 1.1526x over previous
//
#include <hip/hip_runtime.h>
#include <hip/hip_bf16.h>

// Shapes fixed by the reference: B=32, T=1024, F=4096, D=384.
#define B_ 32
#define T_ 1024
#define F_ 4096
#define D_ 384
#define D4_ 96   // D/4 float4 per row

// Native clang vector types — required by __builtin_nontemporal_store.
typedef float vfloat4 __attribute__((ext_vector_type(4)));
typedef int   vint4   __attribute__((ext_vector_type(4)));

// Kernel 1: per-batch run-count prefix sum.
// idx[b][j] = idx[b][j-1] + (align[b][j] != align[b][j-1]), idx[b][0] = 0.
// Equivalent to the reference's sequential pointer walk because align is
// repeat(text, dur) with adjacent text phones guaranteed distinct, so the
// walker's `before` always equals align[j] after step j. text_phone unused.
__global__ __launch_bounds__(256) void scan_idx_kernel(
    const int* __restrict__ align, int* __restrict__ idx)
{
    const int b = blockIdx.x;
    const int t = threadIdx.x;
    const int CHUNK = F_ / 256;  // 16
    const int* a = align + (size_t)b * F_;
    int*       o = idx   + (size_t)b * F_;
    const int start = t * CHUNK;

    int vals[CHUNK];
#pragma unroll
    for (int i = 0; i < CHUNK; ++i) vals[i] = a[start + i];

    int prev = (start == 0) ? vals[0] : a[start - 1];

    int loc[CHUNK];
    int cnt = 0;
#pragma unroll
    for (int i = 0; i < CHUNK; ++i) {
        cnt += (vals[i] != prev) ? 1 : 0;
        loc[i] = cnt;
        prev = vals[i];
    }

    __shared__ int s[256];
    s[t] = cnt;
    __syncthreads();
    for (int off = 1; off < 256; off <<= 1) {
        int v = (t >= off) ? s[t - off] : 0;
        __syncthreads();
        s[t] += v;
        __syncthreads();
    }
    const int base = s[t] - cnt;  // exclusive prefix

#pragma unroll
    for (int i = 0; i < CHUNK; ++i) o[start + i] = base + loc[i];
}

// Kernel 2 (ILP-8, nt stores, NO swizzle) — FINAL, probe reverted.
// Round-8 probe measured this kernel at 38.7 µs marginal = 6.56 TB/s over its
// mandatory 254 MB traffic (192 MiB nt-store + 48 MiB gather + 1.5 MiB vecs)
// = 82% HBM peak, equal to the harness fill kernel's own 81-84% streaming
// ceiling on this chip. Memory roofline reached; remaining iteration time is
// harness-fixed (one 768 MiB poison fill ~120 µs + ~100 µs restore dispatches).
__global__ __launch_bounds__(256) void postnet_kernel(
    const vfloat4* __restrict__ enc,     // [B*T*96]
    const vint4*   __restrict__ idx4,    // [B*F/4]
    const vfloat4* __restrict__ pitch4,  // [B*F/4]
    const vfloat4* __restrict__ beats4,  // [B*F/4]
    const vfloat4* __restrict__ wp, const vfloat4* __restrict__ bp,
    const vfloat4* __restrict__ wb, const vfloat4* __restrict__ bb,
    const vfloat4* __restrict__ wq, const vfloat4* __restrict__ bq,
    vfloat4* __restrict__ out)           // [B*F*96]
{
    const int g   = blockIdx.x * 256 + threadIdx.x;  // < (B*F/8)*96 = 1,572,864
    const int d4  = g % D4_;
    const int rg  = g / D4_;            // 8-frame group id in [0, B*F/8)
    const int rf0 = rg * 8;             // first frame of the group
    const int f0  = rf0 & (F_ - 1);
    const int b   = rf0 >> 12;          // F = 4096 = 2^12

    // Two vector loads each for idx / pitch / beats (frames rf0..rf0+7).
    const vint4   e4a = idx4  [2 * rg],  e4b = idx4  [2 * rg + 1];
    const vfloat4 pva = pitch4[2 * rg],  pvb = pitch4[2 * rg + 1];
    const vfloat4 bva = beats4[2 * rg],  bvb = beats4[2 * rg + 1];

    const vfloat4 w1 = wp[d4], w2 = wb[d4], w3 = wq[d4];
    const vfloat4 osum = bp[d4] + bb[d4] + bq[d4];

    // Issue all 8 gathers up front — independent chains.
    const vfloat4* encb = enc + (size_t)b * T_ * D4_ + d4;
    const vfloat4 ev0 = encb[(size_t)e4a.x * D4_];
    const vfloat4 ev1 = encb[(size_t)e4a.y * D4_];
    const vfloat4 ev2 = encb[(size_t)e4a.z * D4_];
    const vfloat4 ev3 = encb[(size_t)e4a.w * D4_];
    const vfloat4 ev4 = encb[(size_t)e4b.x * D4_];
    const vfloat4 ev5 = encb[(size_t)e4b.y * D4_];
    const vfloat4 ev6 = encb[(size_t)e4b.z * D4_];
    const vfloat4 ev7 = encb[(size_t)e4b.w * D4_];

    const float fv = (float)f0;
    vfloat4 r0 = ev0 + pva.x * w1 + bva.x * w2 + (fv + 0.f) * w3 + osum;
    vfloat4 r1 = ev1 + pva.y * w1 + bva.y * w2 + (fv + 1.f) * w3 + osum;
    vfloat4 r2 = ev2 + pva.z * w1 + bva.z * w2 + (fv + 2.f) * w3 + osum;
    vfloat4 r3 = ev3 + pva.w * w1 + bva.w * w2 + (fv + 3.f) * w3 + osum;
    vfloat4 r4 = ev4 + pvb.x * w1 + bvb.x * w2 + (fv + 4.f) * w3 + osum;
    vfloat4 r5 = ev5 + pvb.y * w1 + bvb.y * w2 + (fv + 5.f) * w3 + osum;
    vfloat4 r6 = ev6 + pvb.z * w1 + bvb.z * w2 + (fv + 6.f) * w3 + osum;
    vfloat4 r7 = ev7 + pvb.w * w1 + bvb.w * w2 + (fv + 7.f) * w3 + osum;

    vfloat4* o = out + (size_t)rf0 * D4_ + d4;
    __builtin_nontemporal_store(r0, o + 0 * D4_);
    __builtin_nontemporal_store(r1, o + 1 * D4_);
    __builtin_nontemporal_store(r2, o + 2 * D4_);
    __builtin_nontemporal_store(r3, o + 3 * D4_);
    __builtin_nontemporal_store(r4, o + 4 * D4_);
    __builtin_nontemporal_store(r5, o + 5 * D4_);
    __builtin_nontemporal_store(r6, o + 6 * D4_);
    __builtin_nontemporal_store(r7, o + 7 * D4_);
}

extern "C" void kernel_launch(void* const* d_in, const int* in_sizes, int n_in,
                              void* d_out, int out_size, void* d_ws, size_t ws_size,
                              hipStream_t stream) {
    const float* enc     = (const float*)d_in[0];   // [B,T,D] f32
    const int*   align   = (const int*)  d_in[1];   // [B,F]
    // d_in[2] = text_phone — unused (see scan_idx_kernel comment)
    const float* pitch   = (const float*)d_in[3];   // [B,F]
    const float* beats   = (const float*)d_in[4];   // [B,F]
    const float* w_pitch = (const float*)d_in[5];
    const float* b_pitch = (const float*)d_in[6];
    const float* w_beats = (const float*)d_in[7];
    const float* b_beats = (const float*)d_in[8];
    const float* w_pos   = (const float*)d_in[9];
    const float* b_pos   = (const float*)d_in[10];

    int* idx_ws = (int*)d_ws;  // B*F ints = 512 KB, 16B-aligned (ws base)

    scan_idx_kernel<<<B_, 256, 0, stream>>>(align, idx_ws);

    const int total = (B_ * F_ / 8) * D4_;    // 1,572,864 threads
    const int blocks = total / 256;           // 6,144 exact
    postnet_kernel<<<blocks, 256, 0, stream>>>(
        (const vfloat4*)enc, (const vint4*)idx_ws,
        (const vfloat4*)pitch, (const vfloat4*)beats,
        (const vfloat4*)w_pitch, (const vfloat4*)b_pitch,
        (const vfloat4*)w_beats, (const vfloat4*)b_beats,
        (const vfloat4*)w_pos,   (const vfloat4*)b_pos,
        (vfloat4*)d_out);
}